// Round 8
// baseline (185.201 us; speedup 1.0000x reference)
//
#include <hip/hip_runtime.h>

// ---------------------------------------------------------------------------
// FlashAttentionV2 on MI355X. bf16 MFMA (16x16x32) throughout.
// R7: flash 32 q-rows/wave (K/V LDS reads reused across 2 q-groups, half the
// barriers), big+small q-tile dispatch pairing; GEMMs BK=64 (32 MFMA/barrier,
// 8-slot XOR swizzle); casts merged into one dispatch.
// ---------------------------------------------------------------------------

typedef __attribute__((ext_vector_type(8))) short bf16x8;
typedef __attribute__((ext_vector_type(4))) short short4v;
typedef __attribute__((ext_vector_type(4))) float f32x4;

#define T_SEQ 2048
#define D_MODEL 1024
#define NHEAD 16
#define DHEAD 64

__device__ inline short f2bf(float f) {
    unsigned u = __float_as_uint(f);
    u += 0x7fffu + ((u >> 16) & 1u);   // RNE
    return (short)(u >> 16);
}

__device__ inline unsigned long long pack4bf(float a, float b, float c, float d) {
    return (unsigned long long)(unsigned short)f2bf(a)
         | ((unsigned long long)(unsigned short)f2bf(b) << 16)
         | ((unsigned long long)(unsigned short)f2bf(c) << 32)
         | ((unsigned long long)(unsigned short)f2bf(d) << 48);
}

__device__ inline f32x4 mfma16(bf16x8 a, bf16x8 b, f32x4 c) {
    return __builtin_amdgcn_mfma_f32_16x16x32_bf16(a, b, c, 0, 0, 0);
}

__device__ inline void gld_lds16(const short* g, short* l) {
    __builtin_amdgcn_global_load_lds(
        (const __attribute__((address_space(1))) void*)g,
        (__attribute__((address_space(3))) void*)l, 16, 0, 0);
}

// ---------------------------------------------------------------------------
// One dispatch: y=0 casts x (4M elems), y=1 casts the 4 weights (4x1M elems,
// dsts contiguous at wdst).
// ---------------------------------------------------------------------------
__global__ __launch_bounds__(256) void cast_all(const float* __restrict__ x,
                                                const float* __restrict__ w0,
                                                const float* __restrict__ w1,
                                                const float* __restrict__ w2,
                                                const float* __restrict__ w3,
                                                short* __restrict__ xdst,
                                                short* __restrict__ wdst) {
    int i = (blockIdx.x * 256 + threadIdx.x) * 4;
    const float* s;
    short* d;
    if (blockIdx.y == 0) {
        s = x + i; d = xdst + i;
    } else {
        int m = i >> 20;   // block-uniform (1024 elems/block)
        s = ((m == 0) ? w0 : (m == 1) ? w1 : (m == 2) ? w2 : w3) + (i & 1048575);
        d = wdst + i;
    }
    float4 v = *(const float4*)s;
    short4v o = { f2bf(v.x), f2bf(v.y), f2bf(v.z), f2bf(v.w) };
    *(short4v*)d = o;
}

// ---------------------------------------------------------------------------
// Fused QKV GEMM: C = A[M,K]*B[N,K]^T, 128x128 tile, BK=64, 32 MFMA/barrier.
// LDS layout: row-major 128 x 64 shorts, 16B chunk slot = c ^ (row&7).
// ---------------------------------------------------------------------------
__global__ __launch_bounds__(256, 3) void gemm_qkv(const short* __restrict__ A,
                                                   const short* __restrict__ B,
                                                   short* __restrict__ C0,
                                                   short* __restrict__ C1,
                                                   short* __restrict__ C2,
                                                   int M, int N, int K) {
    __shared__ short As[8192];   // 16 KB
    __shared__ short Bs[8192];

    const int tid = threadIdx.x;
    const int wave = tid >> 6, lane = tid & 63;
    const int g = lane >> 4, ln = lane & 15;
    const int mh = wave & 1, nh = wave >> 1;
    const int m_base = blockIdx.x * 128;
    const int n_base = blockIdx.y * 128;

    // staging: shot sh covers rows sh*32..+31; thread t: row=sh*32+(t>>3),
    // slot=t&7 holds logical chunk (t&7)^(row&7)
    const int srow = tid >> 3;
    const int scol = ((tid & 7) ^ ((tid >> 3) & 7)) * 8;
    const short* Ag = A + (long)(m_base + srow) * K + scol;
    const short* Bg = B + (long)(n_base + srow) * K + scol;
    const long shK = 32 * (long)K;

    f32x4 acc[4][4];
#pragma unroll
    for (int i = 0; i < 4; i++)
#pragma unroll
        for (int j = 0; j < 4; j++) acc[i][j] = (f32x4){0.f, 0.f, 0.f, 0.f};

    for (int k0 = 0; k0 < K; k0 += 64) {
#pragma unroll
        for (int sh = 0; sh < 4; sh++) {
            gld_lds16(Ag + sh * shK + k0, As + sh * 2048 + tid * 8);
            gld_lds16(Bg + sh * shK + k0, Bs + sh * 2048 + tid * 8);
        }
        __syncthreads();

#pragma unroll
        for (int h = 0; h < 2; h++) {
            bf16x8 a[4], b[4];
#pragma unroll
            for (int mf = 0; mf < 4; mf++) {
                int row = mh * 64 + mf * 16 + ln;
                a[mf] = *(const bf16x8*)(As + row * 64 + (((4 * h + g) ^ (ln & 7)) * 8));
            }
#pragma unroll
            for (int nf = 0; nf < 4; nf++) {
                int row = nh * 64 + nf * 16 + ln;
                b[nf] = *(const bf16x8*)(Bs + row * 64 + (((4 * h + g) ^ (ln & 7)) * 8));
            }
#pragma unroll
            for (int mf = 0; mf < 4; mf++)
#pragma unroll
                for (int nf = 0; nf < 4; nf++)
                    acc[mf][nf] = mfma16(a[mf], b[nf], acc[mf][nf]);
        }
        __syncthreads();
    }

    const int mat = n_base >> 10;   // 0=Q, 1=K, 2=V (uniform per block)
    if (mat < 2) {
        short* dst = mat == 0 ? C0 : C1;
#pragma unroll
        for (int mf = 0; mf < 4; mf++)
#pragma unroll
            for (int nf = 0; nf < 4; nf++)
#pragma unroll
                for (int r = 0; r < 4; r++) {
                    int row = m_base + mh * 64 + mf * 16 + g * 4 + r;
                    int cc = (n_base & 1023) + nh * 64 + nf * 16 + ln;
                    int b_ = row >> 11, t = row & 2047;
                    int h = cc >> 6, d = cc & 63;
                    dst[(((long)(b_ * NHEAD + h) * T_SEQ + t) << 6) + d] =
                        f2bf(acc[mf][nf][r]);
                }
    } else {
        short* dst = C2;   // (B,H,dh,T): pack 4 bf16 along t
#pragma unroll
        for (int mf = 0; mf < 4; mf++)
#pragma unroll
            for (int nf = 0; nf < 4; nf++) {
                short4v pk = { f2bf(acc[mf][nf][0]), f2bf(acc[mf][nf][1]),
                               f2bf(acc[mf][nf][2]), f2bf(acc[mf][nf][3]) };
                int cc = (n_base & 1023) + nh * 64 + nf * 16 + ln;
                int row0 = m_base + mh * 64 + mf * 16 + g * 4;
                int b_ = row0 >> 11, t = row0 & 2047;
                *(short4v*)(&dst[((long)(b_ * 1024 + cc) << 11) + t]) = pk;
            }
    }
}

// ---------------------------------------------------------------------------
// Out-projection GEMM: fp32 C = A[M,K]*B[N,K]^T, 128x64 tile, BK=64.
// ---------------------------------------------------------------------------
__global__ __launch_bounds__(256, 3) void gemm_out(const short* __restrict__ A,
                                                   const short* __restrict__ B,
                                                   float* __restrict__ C,
                                                   int M, int N, int K) {
    __shared__ short As[8192];
    __shared__ short Bs[4096];   // 64 rows x 64 shorts

    const int tid = threadIdx.x;
    const int wave = tid >> 6, lane = tid & 63;
    const int g = lane >> 4, ln = lane & 15;
    const int mh = wave & 1, nh = wave >> 1;
    const int m_base = blockIdx.x * 128;
    const int n_base = blockIdx.y * 64;

    const int srow = tid >> 3;
    const int scol = ((tid & 7) ^ ((tid >> 3) & 7)) * 8;
    const short* Ag = A + (long)(m_base + srow) * K + scol;
    const short* Bg = B + (long)(n_base + srow) * K + scol;
    const long shK = 32 * (long)K;

    f32x4 acc[4][2];
#pragma unroll
    for (int i = 0; i < 4; i++)
#pragma unroll
        for (int j = 0; j < 2; j++) acc[i][j] = (f32x4){0.f, 0.f, 0.f, 0.f};

    for (int k0 = 0; k0 < K; k0 += 64) {
#pragma unroll
        for (int sh = 0; sh < 4; sh++)
            gld_lds16(Ag + sh * shK + k0, As + sh * 2048 + tid * 8);
#pragma unroll
        for (int sh = 0; sh < 2; sh++)
            gld_lds16(Bg + sh * shK + k0, Bs + sh * 2048 + tid * 8);
        __syncthreads();

#pragma unroll
        for (int h = 0; h < 2; h++) {
            bf16x8 a[4], b[2];
#pragma unroll
            for (int mf = 0; mf < 4; mf++) {
                int row = mh * 64 + mf * 16 + ln;
                a[mf] = *(const bf16x8*)(As + row * 64 + (((4 * h + g) ^ (ln & 7)) * 8));
            }
#pragma unroll
            for (int nf = 0; nf < 2; nf++) {
                int row = nh * 32 + nf * 16 + ln;
                b[nf] = *(const bf16x8*)(Bs + row * 64 + (((4 * h + g) ^ (ln & 7)) * 8));
            }
#pragma unroll
            for (int mf = 0; mf < 4; mf++)
#pragma unroll
                for (int nf = 0; nf < 2; nf++)
                    acc[mf][nf] = mfma16(a[mf], b[nf], acc[mf][nf]);
        }
        __syncthreads();
    }

#pragma unroll
    for (int mf = 0; mf < 4; mf++)
#pragma unroll
        for (int nf = 0; nf < 2; nf++)
#pragma unroll
            for (int r = 0; r < 4; r++) {
                int row = m_base + mh * 64 + mf * 16 + g * 4 + r;
                int col = n_base + nh * 32 + nf * 16 + ln;
                C[(long)row * N + col] = acc[mf][nf][r];
            }
}

// ---------------------------------------------------------------------------
// Flash attention (causal), unnormalized softmax, transposed scores,
// 32 q-rows/wave (groups A/B), K/V frags reused across groups.
// Grid 512: qxi=id>>5, qx = qxi<8 ? 15-qxi : qxi-8  (big 256 first, then
// small -> scheduler pairs one big + one small per CU, ~36 tiles each);
// bh = id&31 (XCD pin). Block 256 thr = 4 waves x 32 rows = 128 q-rows.
// ---------------------------------------------------------------------------
__global__ __launch_bounds__(256) void flash_attn(const short* __restrict__ Q,
                                                  const short* __restrict__ Kx,
                                                  const short* __restrict__ Vt,
                                                  short* __restrict__ O) {
    __shared__ short Ks[2][4096];     // [half dh][64 keys][32 shorts], swizzled
    __shared__ short Vs[2][4096];     // [half key][64 dh][32 shorts], swizzled
    __shared__ short ldsP[4][32][68]; // [wave][q 0..31][64 keys]

    const int tid = threadIdx.x;
    const int wv = tid >> 6, lane = tid & 63;
    const int g = lane >> 4, ln = lane & 15;
    const int id = blockIdx.x;
    const int qxi = id >> 5;
    const int qx = (qxi < 8) ? 15 - qxi : qxi - 8;
    const int bh = id & 31;
    const int swz8 = 8 * (g ^ ((ln >> 1) & 3));

    const short* Kp = Kx + (long)bh * (T_SEQ * DHEAD);
    const short* Vp = Vt + (long)bh * (DHEAD * T_SEQ);

    const int sr = tid >> 2;
    const int sc8 = (((tid & 3) ^ ((tid >> 3) & 3))) * 8;
    const int offK0 = sr * 64 + sc8;
    const long offV0 = (long)sr * T_SEQ + sc8;
    const int ldst = tid * 8;

    const float sc = 0.125f * 1.44269504089f;   // 1/sqrt(dh) * log2(e)
    const int nt = 2 * qx + 2;
    const int qrow0 = qx * 128 + wv * 32;

    const short* Qp = Q + ((long)bh * T_SEQ + qrow0) * DHEAD;
    bf16x8 qfA0 = *(const bf16x8*)(Qp + ln * 64 + 8 * g);
    bf16x8 qfA1 = *(const bf16x8*)(Qp + ln * 64 + 32 + 8 * g);
    bf16x8 qfB0 = *(const bf16x8*)(Qp + (16 + ln) * 64 + 8 * g);
    bf16x8 qfB1 = *(const bf16x8*)(Qp + (16 + ln) * 64 + 32 + 8 * g);

    f32x4 oA[4], oB[4];
#pragma unroll
    for (int nf = 0; nf < 4; nf++) {
        oA[nf] = (f32x4){0.f, 0.f, 0.f, 0.f};
        oB[nf] = (f32x4){0.f, 0.f, 0.f, 0.f};
    }
    float liA = 0.f, liB = 0.f;

    // pre-stage tile 0
    gld_lds16(Kp + offK0, &Ks[0][ldst]);
    gld_lds16(Kp + offK0 + 32, &Ks[0][2048 + ldst]);
    gld_lds16(Vp + offV0, &Vs[0][ldst]);
    gld_lds16(Vp + offV0 + 32, &Vs[0][2048 + ldst]);

    int buf = 0;
    for (int i = 0; i < nt; i++) {
        __syncthreads();
        if (i + 1 < nt) {
            const int kO = (i + 1) * 4096 + offK0;
            const long vO = offV0 + (i + 1) * 64;
            gld_lds16(Kp + kO, &Ks[buf ^ 1][ldst]);
            gld_lds16(Kp + kO + 32, &Ks[buf ^ 1][2048 + ldst]);
            gld_lds16(Vp + vO, &Vs[buf ^ 1][ldst]);
            gld_lds16(Vp + vO + 32, &Vs[buf ^ 1][2048 + ldst]);
        }

        // S^T = K * Q^T; K frags read once, used for both q-groups
        f32x4 sA[4], sB[4];
#pragma unroll
        for (int j = 0; j < 4; j++) {
            bf16x8 k0 = *(const bf16x8*)(&Ks[buf][(j * 16 + ln) * 32 + swz8]);
            bf16x8 k1 = *(const bf16x8*)(&Ks[buf][2048 + (j * 16 + ln) * 32 + swz8]);
            sA[j] = mfma16(k0, qfA0, (f32x4){0.f, 0.f, 0.f, 0.f});
            sA[j] = mfma16(k1, qfA1, sA[j]);
            sB[j] = mfma16(k0, qfB0, (f32x4){0.f, 0.f, 0.f, 0.f});
            sB[j] = mfma16(k1, qfB1, sB[j]);
        }

        // V frags (reused for both q-groups)
        bf16x8 vf[4][2];
#pragma unroll
        for (int nf = 0; nf < 4; nf++) {
            vf[nf][0] = *(const bf16x8*)(&Vs[buf][(nf * 16 + ln) * 32 + swz8]);
            vf[nf][1] = *(const bf16x8*)(&Vs[buf][2048 + (nf * 16 + ln) * 32 + swz8]);
        }

        if (i >= 2 * qx) {   // last two tiles cross the diagonal
            const int rel = (i - 2 * qx) * 64;
            const int qA = wv * 32 + ln, qB = qA + 16;
#pragma unroll
            for (int j = 0; j < 4; j++) {
                int kl = rel + 16 * j + 4 * g;
#pragma unroll
                for (int r = 0; r < 4; r++) {
                    if (kl + r > qA) sA[j][r] = -INFINITY;
                    if (kl + r > qB) sB[j][r] = -INFINITY;
                }
            }
        }

#pragma unroll
        for (int j = 0; j < 4; j++) {
            float a0 = __builtin_amdgcn_exp2f(sA[j][0] * sc);
            float a1 = __builtin_amdgcn_exp2f(sA[j][1] * sc);
            float a2 = __builtin_amdgcn_exp2f(sA[j][2] * sc);
            float a3 = __builtin_amdgcn_exp2f(sA[j][3] * sc);
            liA += (a0 + a1) + (a2 + a3);
            *(unsigned long long*)(&ldsP[wv][ln][16 * j + 4 * g]) =
                pack4bf(a0, a1, a2, a3);
            float b0 = __builtin_amdgcn_exp2f(sB[j][0] * sc);
            float b1 = __builtin_amdgcn_exp2f(sB[j][1] * sc);
            float b2 = __builtin_amdgcn_exp2f(sB[j][2] * sc);
            float b3 = __builtin_amdgcn_exp2f(sB[j][3] * sc);
            liB += (b0 + b1) + (b2 + b3);
            *(unsigned long long*)(&ldsP[wv][16 + ln][16 * j + 4 * g]) =
                pack4bf(b0, b1, b2, b3);
        }

        asm volatile("s_waitcnt lgkmcnt(0)" ::: "memory");
        bf16x8 paA0 = *(const bf16x8*)(&ldsP[wv][ln][8 * g]);
        bf16x8 paA1 = *(const bf16x8*)(&ldsP[wv][ln][32 + 8 * g]);
        bf16x8 paB0 = *(const bf16x8*)(&ldsP[wv][16 + ln][8 * g]);
        bf16x8 paB1 = *(const bf16x8*)(&ldsP[wv][16 + ln][32 + 8 * g]);

#pragma unroll
        for (int nf = 0; nf < 4; nf++) {
            oA[nf] = mfma16(paA0, vf[nf][0], oA[nf]);
            oA[nf] = mfma16(paA1, vf[nf][1], oA[nf]);
            oB[nf] = mfma16(paB0, vf[nf][0], oB[nf]);
            oB[nf] = mfma16(paB1, vf[nf][1], oB[nf]);
        }
        buf ^= 1;
    }

    liA += __shfl_xor(liA, 16);
    liA += __shfl_xor(liA, 32);
    liB += __shfl_xor(liB, 16);
    liB += __shfl_xor(liB, 32);

    float lrA[4], lrB[4];
#pragma unroll
    for (int r = 0; r < 4; r++) {
        lrA[r] = 1.f / (__shfl(liA, 4 * g + r) + 1e-9f);
        lrB[r] = 1.f / (__shfl(liB, 4 * g + r) + 1e-9f);
    }

    const int b = bh >> 4, h = bh & 15;
#pragma unroll
    for (int nf = 0; nf < 4; nf++) {
#pragma unroll
        for (int r = 0; r < 4; r++) {
            int rrA = qrow0 + 4 * g + r;
            O[((long)(b * T_SEQ + rrA) << 10) + h * 64 + nf * 16 + ln] =
                f2bf(oA[nf][r] * lrA[r]);
            int rrB = rrA + 16;
            O[((long)(b * T_SEQ + rrB) << 10) + h * 64 + nf * 16 + ln] =
                f2bf(oB[nf][r] * lrB[r]);
        }
    }
}

// ---------------------------------------------------------------------------
extern "C" void kernel_launch(void* const* d_in, const int* in_sizes, int n_in,
                              void* d_out, int out_size, void* d_ws, size_t ws_size,
                              hipStream_t stream) {
    const float* x  = (const float*)d_in[0];
    const float* Wq = (const float*)d_in[1];
    const float* Wk = (const float*)d_in[2];
    const float* Wv = (const float*)d_in[3];
    const float* Wo = (const float*)d_in[4];

    char* ws = (char*)d_ws;
    short* xb  = (short*)(ws + (0ull  << 20));
    short* wqb = (short*)(ws + (8ull  << 20));   // wq,wk,wv,wo contiguous 2MB each
    short* wob = (short*)(ws + (14ull << 20));
    short* Qb  = (short*)(ws + (16ull << 20));   // (B,H,T,64)
    short* Kb  = (short*)(ws + (24ull << 20));   // (B,H,T,64)
    short* Vtb = (short*)(ws + (32ull << 20));   // (B,H,64,T)
    short* Ab  = (short*)(ws + (40ull << 20));   // (B,T,1024)

    cast_all<<<dim3(4096, 2), 256, 0, stream>>>(x, Wq, Wk, Wv, Wo, xb, wqb);

    gemm_qkv<<<dim3(32, 24), 256, 0, stream>>>(xb, wqb, Qb, Kb, Vtb,
                                               4096, 3072, 1024);

    flash_attn<<<512, 256, 0, stream>>>(Qb, Kb, Vtb, Ab);

    gemm_out<<<dim3(32, 16), 256, 0, stream>>>(Ab, wob, (float*)d_out,
                                               4096, 1024, 1024);
}

// Round 9
// 168.533 us; speedup vs baseline: 1.0989x; 1.0989x over previous
//
#include <hip/hip_runtime.h>
#include <hip/hip_bf16.h>

// ---------------------------------------------------------------------------
// FlashAttentionV2 on MI355X. bf16 MFMA (16x16x32) throughout.
// R8: revert to R6 structure (flash 16 rows/wave, grid 1024, GEMM BK=32 —
// R7's 128-row blocks halved occupancy and regressed). New: softmax scale
// folded into Q-projection epilogue; P-pack via v_cvt_pk_bf16_f32
// (__float22bfloat162_rn) cuts ~40% of flash's per-tile VALU chain.
// ---------------------------------------------------------------------------

typedef __attribute__((ext_vector_type(8))) short bf16x8;
typedef __attribute__((ext_vector_type(4))) short short4v;
typedef __attribute__((ext_vector_type(4))) float f32x4;

#define T_SEQ 2048
#define D_MODEL 1024
#define NHEAD 16
#define DHEAD 64
#define QK_SCALE 0.180336879f   // (1/8) * log2(e)

__device__ inline short f2bf(float f) {
    unsigned u = __float_as_uint(f);
    u += 0x7fffu + ((u >> 16) & 1u);   // RNE
    return (short)(u >> 16);
}

__device__ inline unsigned pk2(float a, float b) {
    __hip_bfloat162 h = __float22bfloat162_rn(make_float2(a, b));  // v_cvt_pk_bf16_f32
    return *(unsigned*)&h;
}

__device__ inline unsigned long long pk4(float a, float b, float c, float d) {
    return (unsigned long long)pk2(a, b) | ((unsigned long long)pk2(c, d) << 32);
}

__device__ inline f32x4 mfma16(bf16x8 a, bf16x8 b, f32x4 c) {
    return __builtin_amdgcn_mfma_f32_16x16x32_bf16(a, b, c, 0, 0, 0);
}

__device__ inline void gld_lds16(const short* g, short* l) {
    __builtin_amdgcn_global_load_lds(
        (const __attribute__((address_space(1))) void*)g,
        (__attribute__((address_space(3))) void*)l, 16, 0, 0);
}

// ---------------------------------------------------------------------------
// One dispatch: y=0 casts x (4M elems), y=1 casts the 4 weights.
// ---------------------------------------------------------------------------
__global__ __launch_bounds__(256) void cast_all(const float* __restrict__ x,
                                                const float* __restrict__ w0,
                                                const float* __restrict__ w1,
                                                const float* __restrict__ w2,
                                                const float* __restrict__ w3,
                                                short* __restrict__ xdst,
                                                short* __restrict__ wdst) {
    int i = (blockIdx.x * 256 + threadIdx.x) * 4;
    const float* s;
    short* d;
    if (blockIdx.y == 0) {
        s = x + i; d = xdst + i;
    } else {
        int m = i >> 20;
        s = ((m == 0) ? w0 : (m == 1) ? w1 : (m == 2) ? w2 : w3) + (i & 1048575);
        d = wdst + i;
    }
    float4 v = *(const float4*)s;
    short4v o = { f2bf(v.x), f2bf(v.y), f2bf(v.z), f2bf(v.w) };
    *(short4v*)d = o;
}

// ---------------------------------------------------------------------------
// Fused QKV GEMM: C = A[M,K] * B[N,K]^T, 128x128 tile, BK=32, swizzled LDS.
// Q output is pre-scaled by QK_SCALE (folds softmax scale out of flash).
// ---------------------------------------------------------------------------
__global__ __launch_bounds__(256, 3) void gemm_qkv(const short* __restrict__ A,
                                                   const short* __restrict__ B,
                                                   short* __restrict__ C0,
                                                   short* __restrict__ C1,
                                                   short* __restrict__ C2,
                                                   int M, int N, int K) {
    __shared__ short As[4096];
    __shared__ short Bs[4096];

    const int tid = threadIdx.x;
    const int wave = tid >> 6, lane = tid & 63;
    const int g = lane >> 4, ln = lane & 15;
    const int mh = wave & 1, nh = wave >> 1;
    const int m_base = blockIdx.x * 128;
    const int n_base = blockIdx.y * 128;
    const int swz8 = 8 * (g ^ ((ln >> 1) & 3));

    const int srow = tid >> 2;
    const int scol = (((tid & 3) ^ ((tid >> 3) & 3))) * 8;
    const short* Ag = A + (long)(m_base + srow) * K + scol;
    const short* Bg = B + (long)(n_base + srow) * K + scol;
    const long r64 = 64 * (long)K;

    f32x4 acc[4][4];
#pragma unroll
    for (int i = 0; i < 4; i++)
#pragma unroll
        for (int j = 0; j < 4; j++) acc[i][j] = (f32x4){0.f, 0.f, 0.f, 0.f};

    for (int k0 = 0; k0 < K; k0 += 32) {
        gld_lds16(Ag + k0, As + tid * 8);
        gld_lds16(Ag + r64 + k0, As + 2048 + tid * 8);
        gld_lds16(Bg + k0, Bs + tid * 8);
        gld_lds16(Bg + r64 + k0, Bs + 2048 + tid * 8);
        __syncthreads();

        bf16x8 a[4], b[4];
#pragma unroll
        for (int mf = 0; mf < 4; mf++)
            a[mf] = *(const bf16x8*)(As + (mh * 64 + mf * 16 + ln) * 32 + swz8);
#pragma unroll
        for (int nf = 0; nf < 4; nf++)
            b[nf] = *(const bf16x8*)(Bs + (nh * 64 + nf * 16 + ln) * 32 + swz8);
#pragma unroll
        for (int mf = 0; mf < 4; mf++)
#pragma unroll
            for (int nf = 0; nf < 4; nf++)
                acc[mf][nf] = mfma16(a[mf], b[nf], acc[mf][nf]);
        __syncthreads();
    }

    const int mat = n_base >> 10;   // 0=Q, 1=K, 2=V (uniform per block)
    if (mat < 2) {
        short* dst = mat == 0 ? C0 : C1;
        const float scl = (mat == 0) ? QK_SCALE : 1.f;
#pragma unroll
        for (int mf = 0; mf < 4; mf++)
#pragma unroll
            for (int nf = 0; nf < 4; nf++)
#pragma unroll
                for (int r = 0; r < 4; r++) {
                    int row = m_base + mh * 64 + mf * 16 + g * 4 + r;
                    int cc = (n_base & 1023) + nh * 64 + nf * 16 + ln;
                    int b_ = row >> 11, t = row & 2047;
                    int h = cc >> 6, d = cc & 63;
                    dst[(((long)(b_ * NHEAD + h) * T_SEQ + t) << 6) + d] =
                        f2bf(acc[mf][nf][r] * scl);
                }
    } else {
        short* dst = C2;   // (B,H,dh,T): pack 4 bf16 along t
#pragma unroll
        for (int mf = 0; mf < 4; mf++)
#pragma unroll
            for (int nf = 0; nf < 4; nf++) {
                unsigned long long pk = pk4(acc[mf][nf][0], acc[mf][nf][1],
                                            acc[mf][nf][2], acc[mf][nf][3]);
                int cc = (n_base & 1023) + nh * 64 + nf * 16 + ln;
                int row0 = m_base + mh * 64 + mf * 16 + g * 4;
                int b_ = row0 >> 11, t = row0 & 2047;
                *(unsigned long long*)(&dst[((long)(b_ * 1024 + cc) << 11) + t]) = pk;
            }
    }
}

// ---------------------------------------------------------------------------
// Out-projection GEMM: fp32 C = A[M,K] * B[N,K]^T, 128x64 tile, swizzled LDS.
// ---------------------------------------------------------------------------
__global__ __launch_bounds__(256, 3) void gemm_out(const short* __restrict__ A,
                                                   const short* __restrict__ B,
                                                   float* __restrict__ C,
                                                   int M, int N, int K) {
    __shared__ short As[4096];
    __shared__ short Bs[2048];

    const int tid = threadIdx.x;
    const int wave = tid >> 6, lane = tid & 63;
    const int g = lane >> 4, ln = lane & 15;
    const int mh = wave & 1, nh = wave >> 1;
    const int m_base = blockIdx.x * 128;
    const int n_base = blockIdx.y * 64;
    const int swz8 = 8 * (g ^ ((ln >> 1) & 3));

    const int srow = tid >> 2;
    const int scol = (((tid & 3) ^ ((tid >> 3) & 3))) * 8;
    const short* Ag = A + (long)(m_base + srow) * K + scol;
    const short* Bg = B + (long)(n_base + srow) * K + scol;
    const long r64 = 64 * (long)K;

    f32x4 acc[4][2];
#pragma unroll
    for (int i = 0; i < 4; i++)
#pragma unroll
        for (int j = 0; j < 2; j++) acc[i][j] = (f32x4){0.f, 0.f, 0.f, 0.f};

    for (int k0 = 0; k0 < K; k0 += 32) {
        gld_lds16(Ag + k0, As + tid * 8);
        gld_lds16(Ag + r64 + k0, As + 2048 + tid * 8);
        gld_lds16(Bg + k0, Bs + tid * 8);
        __syncthreads();

        bf16x8 a[4], b[2];
#pragma unroll
        for (int mf = 0; mf < 4; mf++)
            a[mf] = *(const bf16x8*)(As + (mh * 64 + mf * 16 + ln) * 32 + swz8);
#pragma unroll
        for (int nf = 0; nf < 2; nf++)
            b[nf] = *(const bf16x8*)(Bs + (nh * 32 + nf * 16 + ln) * 32 + swz8);
#pragma unroll
        for (int mf = 0; mf < 4; mf++)
#pragma unroll
            for (int nf = 0; nf < 2; nf++)
                acc[mf][nf] = mfma16(a[mf], b[nf], acc[mf][nf]);
        __syncthreads();
    }

#pragma unroll
    for (int mf = 0; mf < 4; mf++)
#pragma unroll
        for (int nf = 0; nf < 2; nf++)
#pragma unroll
            for (int r = 0; r < 4; r++) {
                int row = m_base + mh * 64 + mf * 16 + g * 4 + r;
                int col = n_base + nh * 32 + nf * 16 + ln;
                C[(long)row * N + col] = acc[mf][nf][r];
            }
}

// ---------------------------------------------------------------------------
// Flash attention (causal), unnormalized softmax, transposed scores (R6).
// S^T = K*Q^T; Q pre-scaled by QK_SCALE in gemm_qkv. P-pack via cvt_pk.
// Grid 1024: qx = 31-(id>>5) (LPT), bh = id&31 (XCD pin). 4 waves x 16 rows.
// ---------------------------------------------------------------------------
__global__ __launch_bounds__(256) void flash_attn(const short* __restrict__ Q,
                                                  const short* __restrict__ Kx,
                                                  const short* __restrict__ Vt,
                                                  short* __restrict__ O) {
    __shared__ short Ks[2][4096];    // [half dh][64 keys][32 shorts], swizzled
    __shared__ short Vs[2][4096];    // [half key][64 dh][32 shorts], swizzled
    __shared__ short ldsP[4][16][68];  // [wave][q][64 keys]

    const int tid = threadIdx.x;
    const int wv = tid >> 6, lane = tid & 63;
    const int g = lane >> 4, ln = lane & 15;
    const int id = blockIdx.x;
    const int qx = 31 - (id >> 5);
    const int bh = id & 31;
    const int swz8 = 8 * (g ^ ((ln >> 1) & 3));

    const short* Kp = Kx + (long)bh * (T_SEQ * DHEAD);
    const short* Vp = Vt + (long)bh * (DHEAD * T_SEQ);

    const int sr = tid >> 2;
    const int sc8 = (((tid & 3) ^ ((tid >> 3) & 3))) * 8;
    const int offK0 = sr * 64 + sc8;
    const long offV0 = (long)sr * T_SEQ + sc8;
    const int ldst = tid * 8;

    const int nt = qx + 1;
    const int qrow0 = qx * 64 + wv * 16;

    const short* Qp = Q + ((long)bh * T_SEQ + qrow0) * DHEAD;
    bf16x8 qf0 = *(const bf16x8*)(Qp + ln * 64 + 8 * g);
    bf16x8 qf1 = *(const bf16x8*)(Qp + ln * 64 + 32 + 8 * g);

    f32x4 o[4];
#pragma unroll
    for (int nf = 0; nf < 4; nf++) o[nf] = (f32x4){0.f, 0.f, 0.f, 0.f};
    float li = 0.f;

    // pre-stage tile 0
    gld_lds16(Kp + offK0, &Ks[0][ldst]);
    gld_lds16(Kp + offK0 + 32, &Ks[0][2048 + ldst]);
    gld_lds16(Vp + offV0, &Vs[0][ldst]);
    gld_lds16(Vp + offV0 + 32, &Vs[0][2048 + ldst]);

    int buf = 0;
    for (int i = 0; i < nt; i++) {
        __syncthreads();
        if (i + 1 < nt) {
            const int kO = (i + 1) * 4096 + offK0;
            const long vO = offV0 + (i + 1) * 64;
            gld_lds16(Kp + kO, &Ks[buf ^ 1][ldst]);
            gld_lds16(Kp + kO + 32, &Ks[buf ^ 1][2048 + ldst]);
            gld_lds16(Vp + vO, &Vs[buf ^ 1][ldst]);
            gld_lds16(Vp + vO + 32, &Vs[buf ^ 1][2048 + ldst]);
        }

        // S^T: A = K-frag (key = m), B = Q-frag (q = n); Q pre-scaled
        f32x4 s[4];
#pragma unroll
        for (int j = 0; j < 4; j++) {
            bf16x8 k0 = *(const bf16x8*)(&Ks[buf][(j * 16 + ln) * 32 + swz8]);
            bf16x8 k1 = *(const bf16x8*)(&Ks[buf][2048 + (j * 16 + ln) * 32 + swz8]);
            s[j] = mfma16(k0, qf0, (f32x4){0.f, 0.f, 0.f, 0.f});
            s[j] = mfma16(k1, qf1, s[j]);
        }

        // V loads hoisted (independent of softmax)
        bf16x8 vf[4][2];
#pragma unroll
        for (int nf = 0; nf < 4; nf++) {
            vf[nf][0] = *(const bf16x8*)(&Vs[buf][(nf * 16 + ln) * 32 + swz8]);
            vf[nf][1] = *(const bf16x8*)(&Vs[buf][2048 + (nf * 16 + ln) * 32 + swz8]);
        }

        if (i == nt - 1) {   // diagonal: mask key_local(16j+4g+r) > q_local(16wv+ln)
            const int ql = 16 * wv + ln;
#pragma unroll
            for (int j = 0; j < 4; j++) {
                int kl = 16 * j + 4 * g;
#pragma unroll
                for (int r = 0; r < 4; r++)
                    if (kl + r > ql) s[j][r] = -INFINITY;
            }
        }

#pragma unroll
        for (int j = 0; j < 4; j++) {
            float e0 = __builtin_amdgcn_exp2f(s[j][0]);
            float e1 = __builtin_amdgcn_exp2f(s[j][1]);
            float e2 = __builtin_amdgcn_exp2f(s[j][2]);
            float e3 = __builtin_amdgcn_exp2f(s[j][3]);
            li += (e0 + e1) + (e2 + e3);
            *(unsigned long long*)(&ldsP[wv][ln][16 * j + 4 * g]) =
                pk4(e0, e1, e2, e3);
        }

        asm volatile("s_waitcnt lgkmcnt(0)" ::: "memory");
        bf16x8 pa0 = *(const bf16x8*)(&ldsP[wv][ln][8 * g]);
        bf16x8 pa1 = *(const bf16x8*)(&ldsP[wv][ln][32 + 8 * g]);

#pragma unroll
        for (int nf = 0; nf < 4; nf++) {
            o[nf] = mfma16(pa0, vf[nf][0], o[nf]);
            o[nf] = mfma16(pa1, vf[nf][1], o[nf]);
        }
        buf ^= 1;
    }

    li += __shfl_xor(li, 16);
    li += __shfl_xor(li, 32);

    float lr[4];
#pragma unroll
    for (int r = 0; r < 4; r++)
        lr[r] = 1.f / (__shfl(li, 4 * g + r) + 1e-9f);

    const int b = bh >> 4, h = bh & 15;
#pragma unroll
    for (int nf = 0; nf < 4; nf++) {
#pragma unroll
        for (int r = 0; r < 4; r++) {
            int rr = qrow0 + g * 4 + r;
            O[((long)(b * T_SEQ + rr) << 10) + h * 64 + nf * 16 + ln] =
                f2bf(o[nf][r] * lr[r]);
        }
    }
}

// ---------------------------------------------------------------------------
extern "C" void kernel_launch(void* const* d_in, const int* in_sizes, int n_in,
                              void* d_out, int out_size, void* d_ws, size_t ws_size,
                              hipStream_t stream) {
    const float* x  = (const float*)d_in[0];
    const float* Wq = (const float*)d_in[1];
    const float* Wk = (const float*)d_in[2];
    const float* Wv = (const float*)d_in[3];
    const float* Wo = (const float*)d_in[4];

    char* ws = (char*)d_ws;
    short* xb  = (short*)(ws + (0ull  << 20));
    short* wqb = (short*)(ws + (8ull  << 20));   // wq,wk,wv,wo contiguous 2MB each
    short* wob = (short*)(ws + (14ull << 20));
    short* Qb  = (short*)(ws + (16ull << 20));   // (B,H,T,64), pre-scaled
    short* Kb  = (short*)(ws + (24ull << 20));   // (B,H,T,64)
    short* Vtb = (short*)(ws + (32ull << 20));   // (B,H,64,T)
    short* Ab  = (short*)(ws + (40ull << 20));   // (B,T,1024)

    cast_all<<<dim3(4096, 2), 256, 0, stream>>>(x, Wq, Wk, Wv, Wo, xb, wqb);

    gemm_qkv<<<dim3(32, 24), 256, 0, stream>>>(xb, wqb, Qb, Kb, Vtb,
                                               4096, 3072, 1024);

    flash_attn<<<1024, 256, 0, stream>>>(Qb, Kb, Vtb, Ab);

    gemm_out<<<dim3(32, 16), 256, 0, stream>>>(Ab, wob, (float*)d_out,
                                               4096, 1024, 1024);
}